// Round 5
// baseline (379.116 us; speedup 1.0000x reference)
//
#include <hip/hip_runtime.h>
#include <hip/hip_bf16.h>

// MultiSelfAttention: B=4, S=2048, D_MODEL=1024, H=16, Dk=64.
// cvt fp32->bf16 -> QKV proj GEMMs (bf16 MFMA) -> flash attention
// (double-buffered LDS staging, swapped QK^T, in-register P, defer-max)
// -> O proj GEMM -> fp32 out.

typedef __attribute__((ext_vector_type(8))) short short8;
typedef __attribute__((ext_vector_type(4))) float f32x4;

#define DEV __device__ __forceinline__

DEV ushort f2bf(float f) {
  union { float f; unsigned u; } v; v.f = f;
  return (ushort)((v.u + 0x7fffu + ((v.u >> 16) & 1u)) >> 16);
}

DEV void gload_lds16(const void* g, void* lds) {
  __builtin_amdgcn_global_load_lds(
      (const __attribute__((address_space(1))) void*)g,
      (__attribute__((address_space(3))) void*)lds, 16, 0, 0);
}

// ---------------- fp32 -> bf16 convert ----------------
__global__ void cvt_kernel(const float* __restrict__ in, ushort* __restrict__ out, int n4) {
  int stride = gridDim.x * blockDim.x;
  for (int i = blockIdx.x * blockDim.x + threadIdx.x; i < n4; i += stride) {
    float4 v = ((const float4*)in)[i];
    ushort4 o;
    o.x = f2bf(v.x); o.y = f2bf(v.y); o.z = f2bf(v.z); o.w = f2bf(v.w);
    ((ushort4*)out)[i] = o;
  }
}

// ---------------- GEMM: C[m,n] = sum_k X[m,k]*W[n,k] + bias[n] ----------------
// MODE 0: out bf16 [b*16+h][s][d]   (Q,K head layout)
// MODE 1: out bf16 [b*16+h][d][s]   (V transposed layout)
// MODE 2: out fp32 [m][n]           (final output)
template<int MODE>
__global__ __launch_bounds__(256) void gemm_bt(
    const ushort* __restrict__ X, const ushort* __restrict__ W,
    const float* __restrict__ bias, void* __restrict__ out)
{
  constexpr int K = 1024, N = 1024;
  __shared__ __align__(16) ushort As[128 * 32];
  __shared__ __align__(16) ushort Bs[128 * 32];
  const int t = threadIdx.x;
  const int w = t >> 6, l = t & 63;
  const int bid = blockIdx.x;
  const int m0 = (bid >> 3) * 128, n0 = (bid & 7) * 128;
  const int wm = (w >> 1) * 64, wn = (w & 1) * 64;

  const f32x4 zero = {0.f, 0.f, 0.f, 0.f};
  f32x4 acc[4][4];
#pragma unroll
  for (int i = 0; i < 4; i++)
#pragma unroll
    for (int j = 0; j < 4; j++) acc[i][j] = zero;

  const int srow = l >> 2;
  const int scolb = (l & 3) * 16;

  for (int kt = 0; kt < K; kt += 32) {
    __syncthreads();
#pragma unroll
    for (int c = w; c < 8; c += 4) {
      int row = c * 16 + srow;
      gload_lds16((const char*)X + ((size_t)(m0 + row) * K + kt) * 2 + scolb,
                  (char*)As + c * 1024);
      gload_lds16((const char*)W + ((size_t)(n0 + row) * K + kt) * 2 + scolb,
                  (char*)Bs + c * 1024);
    }
    __syncthreads();

    short8 af[4], bf[4];
#pragma unroll
    for (int i = 0; i < 4; i++) {
      af[i] = *(const short8*)((const char*)As + (wm + i * 16 + (l & 15)) * 64 + (l >> 4) * 16);
      bf[i] = *(const short8*)((const char*)Bs + (wn + i * 16 + (l & 15)) * 64 + (l >> 4) * 16);
    }
#pragma unroll
    for (int i = 0; i < 4; i++)
#pragma unroll
      for (int j = 0; j < 4; j++)
        acc[i][j] = __builtin_amdgcn_mfma_f32_16x16x32_bf16(af[i], bf[j], acc[i][j], 0, 0, 0);
  }

#pragma unroll
  for (int i = 0; i < 4; i++) {
    int mbase = m0 + wm + i * 16 + ((l >> 4) << 2);
#pragma unroll
    for (int j = 0; j < 4; j++) {
      int n = n0 + wn + j * 16 + (l & 15);
      float bv = bias[n];
#pragma unroll
      for (int r = 0; r < 4; r++) {
        int m = mbase + r;
        float v = acc[i][j][r] + bv;
        if (MODE == 2) {
          ((float*)out)[(size_t)m * N + n] = v;
        } else {
          int b = m >> 11, s = m & 2047;
          int h = n >> 6, d = n & 63;
          size_t off;
          if (MODE == 0) off = ((size_t)(b * 16 + h) * 2048 + s) * 64 + d;
          else           off = ((size_t)(b * 16 + h) * 64 + d) * 2048 + s;
          ((ushort*)out)[off] = f2bf(v);
        }
      }
    }
  }
}

// ---------------- Flash attention (dbuf staging, swapped QK^T, in-register P) ----------------
// Qh,Kh: [64][2048][64] bf16.  Vt: [64][64][2048] bf16.  ctx: [4][2048][16][64] bf16.
// 8 waves x 16 q-rows = 128 q-rows/block; 512 threads. KV tiles of 64,
// double-buffered in LDS: STAGE(next) issued before compute(cur), one barrier
// per tile. Scores in log2 domain (Q pre-scaled by log2(e)/8).
__global__ __launch_bounds__(512, 8) void attn_kernel(
    const ushort* __restrict__ Qh, const ushort* __restrict__ Kh,
    const ushort* __restrict__ Vt, ushort* __restrict__ ctx)
{
  __shared__ __align__(16) ushort Ks[2 * 64 * 64];
  __shared__ __align__(16) ushort Vs[2 * 64 * 64];
  const int t = threadIdx.x, w = t >> 6, l = t & 63;
  const int g = l >> 4, g1 = g >> 1, g0 = g & 1, qi = l & 15;
  const int bh = blockIdx.y;
  const int q0 = blockIdx.x * 128 + w * 16;
  const ushort* Qb = Qh + (size_t)bh * 2048 * 64;
  const ushort* Kb = Kh + (size_t)bh * 2048 * 64;
  const ushort* Vb = Vt + (size_t)bh * 64 * 2048;

  // Q fragment (B operand: col=q=qi, k=d=g*8+j), pre-scaled by log2(e)/8
  short8 qa[2];
  {
    const ushort* p = Qb + (size_t)(q0 + qi) * 64 + g * 8;
    qa[0] = *(const short8*)(p);
    qa[1] = *(const short8*)(p + 32);
    const float SC = 0.18033688f;  // log2(e)/8
#pragma unroll
    for (int h = 0; h < 2; h++)
#pragma unroll
      for (int j = 0; j < 8; j++) {
        union { float f; unsigned u; } v;
        v.u = ((unsigned)(ushort)qa[h][j]) << 16;
        v.f *= SC;
        qa[h][j] = (short)f2bf(v.f);
      }
  }

  const f32x4 zero = {0.f, 0.f, 0.f, 0.f};
  f32x4 o_acc[4];
#pragma unroll
  for (int i = 0; i < 4; i++) o_acc[i] = zero;
  float m = -1e30f, lrow = 0.f;  // per-lane state for q = qi (log2 domain)

  // staging: each wave stages chunk w (8 rows) of K and of V, 1 load/thread each.
  // LDS linear dest, pre-swizzled global source (swz: byte ^= (row&7)<<4).
  const int srow8 = l >> 3;                       // row within chunk
  const int scolb = ((l & 7) ^ (l >> 3)) << 4;    // pre-swizzled byte col
  const char* kgp = (const char*)Kb + (size_t)(w * 8 + srow8) * 128 + scolb;
  const char* vgp = (const char*)Vb + (size_t)(w * 8 + srow8) * 4096 + scolb;
  char* ksw = (char*)Ks + w * 1024;
  char* vsw = (char*)Vs + w * 1024;

  // prologue: stage tile 0 into buffer 0
  gload_lds16(kgp, ksw);
  gload_lds16(vgp, vsw);
  __syncthreads();

  for (int it = 0; it < 32; it++) {
    const int cur = it & 1;
    // issue next-tile staging into the other buffer (its readers finished at
    // the previous barrier); lands before anyone reads it (barrier below
    // drains vmcnt).
    if (it < 31) {
      size_t kv = (size_t)(it + 1);
      gload_lds16(kgp + kv * 8192, ksw + (cur ^ 1) * 8192);
      gload_lds16(vgp + kv * 128, vsw + (cur ^ 1) * 8192);
    }
    const char* KsB = (const char*)Ks + cur * 8192;
    const char* VsB = (const char*)Vs + cur * 8192;

    // S^T = K Q^T  (D: row=kv=16*kvf+g*4+r, col=q=qi), log2 domain
    f32x4 sf[4];
    __builtin_amdgcn_s_setprio(1);
#pragma unroll
    for (int kvf = 0; kvf < 4; kvf++) {
      int row = kvf * 16 + qi;
      int sw = (row & 7) << 4;
      int base = row * 128 + g * 16;
      short8 k0 = *(const short8*)(KsB + (base ^ sw));
      short8 k1 = *(const short8*)(KsB + ((base + 64) ^ sw));
      f32x4 s = zero;
      s = __builtin_amdgcn_mfma_f32_16x16x32_bf16(k0, qa[0], s, 0, 0, 0);
      s = __builtin_amdgcn_mfma_f32_16x16x32_bf16(k1, qa[1], s, 0, 0, 0);
      sf[kvf] = s;
    }
    __builtin_amdgcn_s_setprio(0);

    // online softmax, in-lane over 16 kv + 2 shfls across kv-groups
    float pmax = -1e30f;
#pragma unroll
    for (int kvf = 0; kvf < 4; kvf++)
#pragma unroll
      for (int r = 0; r < 4; r++) pmax = fmaxf(pmax, sf[kvf][r]);
    pmax = fmaxf(pmax, __shfl_xor(pmax, 16));
    pmax = fmaxf(pmax, __shfl_xor(pmax, 32));

    if (__any(pmax > m + 8.f)) {  // defer-max: rescale only when needed
      float mnew = fmaxf(m, pmax);
      float facq = exp2f(m - mnew);
      m = mnew;
      lrow *= facq;
#pragma unroll
      for (int r = 0; r < 4; r++) {
        float f = __shfl(facq, g * 4 + r);
#pragma unroll
        for (int df = 0; df < 4; df++) o_acc[df][r] *= f;
      }
    }

    float lsum = 0.f;
#pragma unroll
    for (int kvf = 0; kvf < 4; kvf++)
#pragma unroll
      for (int r = 0; r < 4; r++) {
        float p = exp2f(sf[kvf][r] - m);
        sf[kvf][r] = p;
        lsum += p;
      }
    lsum += __shfl_xor(lsum, 16);
    lsum += __shfl_xor(lsum, 32);
    lrow += lsum;

    // pack P to bf16 pairs: w8[kvf][p] = kv pair (16*kvf+4*g+2p, +1)
    unsigned w8[4][2];
#pragma unroll
    for (int kvf = 0; kvf < 4; kvf++)
#pragma unroll
      for (int p = 0; p < 2; p++)
        asm("v_cvt_pk_bf16_f32 %0, %1, %2"
            : "=v"(w8[kvf][p]) : "v"(sf[kvf][2 * p]), "v"(sf[kvf][2 * p + 1]));

    // redistribute to PV A-frag layout: lane needs kv = 32h + 8g + {0..7} for its q
    unsigned pw[2][4];
#pragma unroll
    for (int c2 = 0; c2 < 2; c2++)
#pragma unroll
      for (int c1 = 0; c1 < 2; c1++)
#pragma unroll
        for (int c0 = 0; c0 < 2; c0++) {
          unsigned prov = w8[2 * c2 + (c0 ^ g0)][c1];
          int src = (((g0 << 1) | (c0 ^ g1)) << 4) + qi;
          unsigned r = (unsigned)__shfl((int)prov, src);
          if (g1 == 0) pw[c2][(c0 << 1) | c1] = r;
          else         pw[c2][((c0 ^ 1) << 1) | c1] = r;
        }
    union { unsigned u[4]; short8 s; } pa0, pa1;
#pragma unroll
    for (int i = 0; i < 4; i++) { pa0.u[i] = pw[0][i]; pa1.u[i] = pw[1][i]; }

    // O += P V   (A=P: row=q=qi, k=kv; B=Vs[d][kv]: col=d, k=kv)
    __builtin_amdgcn_s_setprio(1);
#pragma unroll
    for (int df = 0; df < 4; df++) {
      int row = df * 16 + qi;
      int sw = (row & 7) << 4;
      int base = row * 128 + g * 16;
      short8 v0 = *(const short8*)(VsB + (base ^ sw));
      short8 v1 = *(const short8*)(VsB + ((base + 64) ^ sw));
      o_acc[df] = __builtin_amdgcn_mfma_f32_16x16x32_bf16(pa0.s, v0, o_acc[df], 0, 0, 0);
      o_acc[df] = __builtin_amdgcn_mfma_f32_16x16x32_bf16(pa1.s, v1, o_acc[df], 0, 0, 0);
    }
    __builtin_amdgcn_s_setprio(0);

    // publish next buffer (implicit vmcnt(0)+lgkmcnt(0) drain), close this one
    __syncthreads();
  }

  // epilogue: ctx[b][s][h][d] = o_acc / l
  float linv = 1.f / lrow;
  const int b = bh >> 4, h = bh & 15;
#pragma unroll
  for (int r = 0; r < 4; r++) {
    int q = q0 + g * 4 + r;
    float inv = __shfl(linv, g * 4 + r);
#pragma unroll
    for (int df = 0; df < 4; df++) {
      int d = df * 16 + qi;
      size_t off = (((size_t)b * 2048 + q) * 16 + h) * 64 + d;
      ctx[off] = f2bf(o_acc[df][r] * inv);
    }
  }
}

extern "C" void kernel_launch(void* const* d_in, const int* in_sizes, int n_in,
                              void* d_out, int out_size, void* d_ws, size_t ws_size,
                              hipStream_t stream) {
  const float* q  = (const float*)d_in[0];
  const float* k  = (const float*)d_in[1];
  const float* v  = (const float*)d_in[2];
  const float* Wq = (const float*)d_in[3];
  const float* bq = (const float*)d_in[4];
  const float* Wk = (const float*)d_in[5];
  const float* bk = (const float*)d_in[6];
  const float* Wv = (const float*)d_in[7];
  const float* bv = (const float*)d_in[8];
  const float* Wo = (const float*)d_in[9];
  const float* bo = (const float*)d_in[10];

  const size_t MSZ = (size_t)8192 * 1024;
  const size_t WSZ = (size_t)1024 * 1024;
  char* ws = (char*)d_ws;
  ushort* Xbuf = (ushort*)ws;
  ushort* w16[4];
  w16[0] = Xbuf + MSZ;
  w16[1] = w16[0] + WSZ;
  w16[2] = w16[1] + WSZ;
  w16[3] = w16[2] + WSZ;
  ushort* Qhb = w16[3] + WSZ;
  ushort* Khb = Qhb + MSZ;
  ushort* Vtb = Khb + MSZ;
  ushort* ctx = Xbuf;

  const float* Wsrc[4] = {Wq, Wk, Wv, Wo};
  for (int i = 0; i < 4; i++)
    cvt_kernel<<<512, 256, 0, stream>>>(Wsrc[i], w16[i], (int)(WSZ / 4));

  cvt_kernel<<<2048, 256, 0, stream>>>(q, Xbuf, (int)(MSZ / 4));
  gemm_bt<0><<<512, 256, 0, stream>>>(Xbuf, w16[0], bq, Qhb);
  cvt_kernel<<<2048, 256, 0, stream>>>(k, Xbuf, (int)(MSZ / 4));
  gemm_bt<0><<<512, 256, 0, stream>>>(Xbuf, w16[1], bk, Khb);
  cvt_kernel<<<2048, 256, 0, stream>>>(v, Xbuf, (int)(MSZ / 4));
  gemm_bt<1><<<512, 256, 0, stream>>>(Xbuf, w16[2], bv, Vtb);

  attn_kernel<<<dim3(16, 64), 512, 0, stream>>>(Qhb, Khb, Vtb, ctx);

  gemm_bt<2><<<512, 256, 0, stream>>>(ctx, w16[3], bo, (float*)d_out);
}

// Round 6
// 336.576 us; speedup vs baseline: 1.1264x; 1.1264x over previous
//
#include <hip/hip_runtime.h>
#include <hip/hip_bf16.h>

// MultiSelfAttention: B=4, S=2048, D_MODEL=1024, H=16, Dk=64.
// cvt fp32->bf16 -> QKV proj GEMMs (bf16 MFMA) -> flash attention
// (double-buffered LDS staging, XCD-swizzled grid, swapped QK^T,
//  in-register P, defer-max) -> O proj GEMM -> fp32 out.

typedef __attribute__((ext_vector_type(8))) short short8;
typedef __attribute__((ext_vector_type(4))) float f32x4;

#define DEV __device__ __forceinline__

DEV ushort f2bf(float f) {
  union { float f; unsigned u; } v; v.f = f;
  return (ushort)((v.u + 0x7fffu + ((v.u >> 16) & 1u)) >> 16);
}

DEV void gload_lds16(const void* g, void* lds) {
  __builtin_amdgcn_global_load_lds(
      (const __attribute__((address_space(1))) void*)g,
      (__attribute__((address_space(3))) void*)lds, 16, 0, 0);
}

// ---------------- fp32 -> bf16 convert ----------------
__global__ void cvt_kernel(const float* __restrict__ in, ushort* __restrict__ out, int n4) {
  int stride = gridDim.x * blockDim.x;
  for (int i = blockIdx.x * blockDim.x + threadIdx.x; i < n4; i += stride) {
    float4 v = ((const float4*)in)[i];
    ushort4 o;
    o.x = f2bf(v.x); o.y = f2bf(v.y); o.z = f2bf(v.z); o.w = f2bf(v.w);
    ((ushort4*)out)[i] = o;
  }
}

// ---------------- GEMM: C[m,n] = sum_k X[m,k]*W[n,k] + bias[n] ----------------
// MODE 0: out bf16 [b*16+h][s][d]   (Q,K head layout)
// MODE 1: out bf16 [b*16+h][d][s]   (V transposed layout)
// MODE 2: out fp32 [m][n]           (final output)
template<int MODE>
__global__ __launch_bounds__(256) void gemm_bt(
    const ushort* __restrict__ X, const ushort* __restrict__ W,
    const float* __restrict__ bias, void* __restrict__ out)
{
  constexpr int K = 1024, N = 1024;
  __shared__ __align__(16) ushort As[128 * 32];
  __shared__ __align__(16) ushort Bs[128 * 32];
  const int t = threadIdx.x;
  const int w = t >> 6, l = t & 63;
  const int bid = blockIdx.x;
  const int m0 = (bid >> 3) * 128, n0 = (bid & 7) * 128;
  const int wm = (w >> 1) * 64, wn = (w & 1) * 64;

  const f32x4 zero = {0.f, 0.f, 0.f, 0.f};
  f32x4 acc[4][4];
#pragma unroll
  for (int i = 0; i < 4; i++)
#pragma unroll
    for (int j = 0; j < 4; j++) acc[i][j] = zero;

  const int srow = l >> 2;
  const int scolb = (l & 3) * 16;

  for (int kt = 0; kt < K; kt += 32) {
    __syncthreads();
#pragma unroll
    for (int c = w; c < 8; c += 4) {
      int row = c * 16 + srow;
      gload_lds16((const char*)X + ((size_t)(m0 + row) * K + kt) * 2 + scolb,
                  (char*)As + c * 1024);
      gload_lds16((const char*)W + ((size_t)(n0 + row) * K + kt) * 2 + scolb,
                  (char*)Bs + c * 1024);
    }
    __syncthreads();

    short8 af[4], bf[4];
#pragma unroll
    for (int i = 0; i < 4; i++) {
      af[i] = *(const short8*)((const char*)As + (wm + i * 16 + (l & 15)) * 64 + (l >> 4) * 16);
      bf[i] = *(const short8*)((const char*)Bs + (wn + i * 16 + (l & 15)) * 64 + (l >> 4) * 16);
    }
#pragma unroll
    for (int i = 0; i < 4; i++)
#pragma unroll
      for (int j = 0; j < 4; j++)
        acc[i][j] = __builtin_amdgcn_mfma_f32_16x16x32_bf16(af[i], bf[j], acc[i][j], 0, 0, 0);
  }

#pragma unroll
  for (int i = 0; i < 4; i++) {
    int mbase = m0 + wm + i * 16 + ((l >> 4) << 2);
#pragma unroll
    for (int j = 0; j < 4; j++) {
      int n = n0 + wn + j * 16 + (l & 15);
      float bv = bias[n];
#pragma unroll
      for (int r = 0; r < 4; r++) {
        int m = mbase + r;
        float v = acc[i][j][r] + bv;
        if (MODE == 2) {
          ((float*)out)[(size_t)m * N + n] = v;
        } else {
          int b = m >> 11, s = m & 2047;
          int h = n >> 6, d = n & 63;
          size_t off;
          if (MODE == 0) off = ((size_t)(b * 16 + h) * 2048 + s) * 64 + d;
          else           off = ((size_t)(b * 16 + h) * 64 + d) * 2048 + s;
          ((ushort*)out)[off] = f2bf(v);
        }
      }
    }
  }
}

// ---------------- Flash attention (dbuf staging, XCD swizzle, swapped QK^T) ----------------
// Qh,Kh: [64][2048][64] bf16.  Vt: [64][64][2048] bf16.  ctx: [4][2048][16][64] bf16.
// 4 waves x 16 q-rows = 64 q-rows/block; 2048 blocks linearized; XCD-swizzled
// so each XCD's L2 serves 8 bh (4 MB KV working set). KV tiles of 64,
// double-buffered in LDS: STAGE(next) issued before compute(cur), one barrier
// per tile. Scores in log2 domain (Q pre-scaled by log2(e)/8).
__global__ __launch_bounds__(256, 6) void attn_kernel(
    const ushort* __restrict__ Qh, const ushort* __restrict__ Kh,
    const ushort* __restrict__ Vt, ushort* __restrict__ ctx)
{
  __shared__ __align__(16) ushort Ks[2 * 64 * 64];
  __shared__ __align__(16) ushort Vs[2 * 64 * 64];
  const int t = threadIdx.x, w = t >> 6, l = t & 63;
  const int g = l >> 4, g1 = g >> 1, g0 = g & 1, qi = l & 15;
  // XCD-aware bijective swizzle: physical p -> logical (p%8)*256 + p/8.
  // XCD x then owns logical ids [256x, 256x+256) = bh [8x, 8x+8) entirely.
  const int p = blockIdx.x;
  const int logical = (p & 7) * 256 + (p >> 3);
  const int bh = logical >> 5;
  const int q0 = (logical & 31) * 64 + w * 16;
  const ushort* Qb = Qh + (size_t)bh * 2048 * 64;
  const ushort* Kb = Kh + (size_t)bh * 2048 * 64;
  const ushort* Vb = Vt + (size_t)bh * 64 * 2048;

  // Q fragment (B operand: col=q=qi, k=d=g*8+j), pre-scaled by log2(e)/8
  short8 qa[2];
  {
    const ushort* p_ = Qb + (size_t)(q0 + qi) * 64 + g * 8;
    qa[0] = *(const short8*)(p_);
    qa[1] = *(const short8*)(p_ + 32);
    const float SC = 0.18033688f;  // log2(e)/8
#pragma unroll
    for (int h = 0; h < 2; h++)
#pragma unroll
      for (int j = 0; j < 8; j++) {
        union { float f; unsigned u; } v;
        v.u = ((unsigned)(ushort)qa[h][j]) << 16;
        v.f *= SC;
        qa[h][j] = (short)f2bf(v.f);
      }
  }

  const f32x4 zero = {0.f, 0.f, 0.f, 0.f};
  f32x4 o_acc[4];
#pragma unroll
  for (int i = 0; i < 4; i++) o_acc[i] = zero;
  float m = -1e30f, lrow = 0.f;  // per-lane state for q = qi (log2 domain)

  // staging: 4 waves x 4 loads/thread per tile (K chunks w, w+4; V chunks w, w+4).
  // LDS linear dest, pre-swizzled global source (swz: byte ^= (row&7)<<4).
  const int srow8 = l >> 3;                       // row within 8-row chunk
  const int scolb = ((l & 7) ^ (l >> 3)) << 4;    // pre-swizzled byte col
  const char* kgp0 = (const char*)Kb + (size_t)(w * 8 + srow8) * 128 + scolb;
  const char* kgp1 = kgp0 + 32 * 128;
  const char* vgp0 = (const char*)Vb + (size_t)(w * 8 + srow8) * 4096 + scolb;
  const char* vgp1 = vgp0 + (size_t)32 * 4096;
  char* ksw0 = (char*)Ks + w * 1024;
  char* vsw0 = (char*)Vs + w * 1024;

  // prologue: stage tile 0 into buffer 0
  gload_lds16(kgp0, ksw0);
  gload_lds16(kgp1, ksw0 + 4096);
  gload_lds16(vgp0, vsw0);
  gload_lds16(vgp1, vsw0 + 4096);
  __syncthreads();

  for (int it = 0; it < 32; it++) {
    const int cur = it & 1;
    // issue next-tile staging into the other buffer (its readers finished at
    // the previous barrier); lands before anyone reads it (barrier below
    // drains vmcnt).
    if (it < 31) {
      size_t kv = (size_t)(it + 1);
      char* kd = ksw0 + (cur ^ 1) * 8192;
      char* vd = vsw0 + (cur ^ 1) * 8192;
      gload_lds16(kgp0 + kv * 8192, kd);
      gload_lds16(kgp1 + kv * 8192, kd + 4096);
      gload_lds16(vgp0 + kv * 128, vd);
      gload_lds16(vgp1 + kv * 128, vd + 4096);
    }
    const char* KsB = (const char*)Ks + cur * 8192;
    const char* VsB = (const char*)Vs + cur * 8192;

    // S^T = K Q^T  (D: row=kv=16*kvf+g*4+r, col=q=qi), log2 domain
    f32x4 sf[4];
    __builtin_amdgcn_s_setprio(1);
#pragma unroll
    for (int kvf = 0; kvf < 4; kvf++) {
      int row = kvf * 16 + qi;
      int sw = (row & 7) << 4;
      int base = row * 128 + g * 16;
      short8 k0 = *(const short8*)(KsB + (base ^ sw));
      short8 k1 = *(const short8*)(KsB + ((base + 64) ^ sw));
      f32x4 s = zero;
      s = __builtin_amdgcn_mfma_f32_16x16x32_bf16(k0, qa[0], s, 0, 0, 0);
      s = __builtin_amdgcn_mfma_f32_16x16x32_bf16(k1, qa[1], s, 0, 0, 0);
      sf[kvf] = s;
    }
    __builtin_amdgcn_s_setprio(0);

    // online softmax, in-lane over 16 kv + 2 shfls across kv-groups
    float pmax = -1e30f;
#pragma unroll
    for (int kvf = 0; kvf < 4; kvf++)
#pragma unroll
      for (int r = 0; r < 4; r++) pmax = fmaxf(pmax, sf[kvf][r]);
    pmax = fmaxf(pmax, __shfl_xor(pmax, 16));
    pmax = fmaxf(pmax, __shfl_xor(pmax, 32));

    if (__any(pmax > m + 8.f)) {  // defer-max: rescale only when needed
      float mnew = fmaxf(m, pmax);
      float facq = exp2f(m - mnew);
      m = mnew;
      lrow *= facq;
#pragma unroll
      for (int r = 0; r < 4; r++) {
        float f = __shfl(facq, g * 4 + r);
#pragma unroll
        for (int df = 0; df < 4; df++) o_acc[df][r] *= f;
      }
    }

    float lsum = 0.f;
#pragma unroll
    for (int kvf = 0; kvf < 4; kvf++)
#pragma unroll
      for (int r = 0; r < 4; r++) {
        float p_ = exp2f(sf[kvf][r] - m);
        sf[kvf][r] = p_;
        lsum += p_;
      }
    lsum += __shfl_xor(lsum, 16);
    lsum += __shfl_xor(lsum, 32);
    lrow += lsum;

    // pack P to bf16 pairs: w8[kvf][p] = kv pair (16*kvf+4*g+2p, +1)
    unsigned w8[4][2];
#pragma unroll
    for (int kvf = 0; kvf < 4; kvf++)
#pragma unroll
      for (int pp = 0; pp < 2; pp++)
        asm("v_cvt_pk_bf16_f32 %0, %1, %2"
            : "=v"(w8[kvf][pp]) : "v"(sf[kvf][2 * pp]), "v"(sf[kvf][2 * pp + 1]));

    // redistribute to PV A-frag layout: lane needs kv = 32h + 8g + {0..7} for its q
    unsigned pw[2][4];
#pragma unroll
    for (int c2 = 0; c2 < 2; c2++)
#pragma unroll
      for (int c1 = 0; c1 < 2; c1++)
#pragma unroll
        for (int c0 = 0; c0 < 2; c0++) {
          unsigned prov = w8[2 * c2 + (c0 ^ g0)][c1];
          int src = (((g0 << 1) | (c0 ^ g1)) << 4) + qi;
          unsigned r = (unsigned)__shfl((int)prov, src);
          if (g1 == 0) pw[c2][(c0 << 1) | c1] = r;
          else         pw[c2][((c0 ^ 1) << 1) | c1] = r;
        }
    union { unsigned u[4]; short8 s; } pa0, pa1;
#pragma unroll
    for (int i = 0; i < 4; i++) { pa0.u[i] = pw[0][i]; pa1.u[i] = pw[1][i]; }

    // O += P V   (A=P: row=q=qi, k=kv; B=Vs[d][kv]: col=d, k=kv)
    __builtin_amdgcn_s_setprio(1);
#pragma unroll
    for (int df = 0; df < 4; df++) {
      int row = df * 16 + qi;
      int sw = (row & 7) << 4;
      int base = row * 128 + g * 16;
      short8 v0 = *(const short8*)(VsB + (base ^ sw));
      short8 v1 = *(const short8*)(VsB + ((base + 64) ^ sw));
      o_acc[df] = __builtin_amdgcn_mfma_f32_16x16x32_bf16(pa0.s, v0, o_acc[df], 0, 0, 0);
      o_acc[df] = __builtin_amdgcn_mfma_f32_16x16x32_bf16(pa1.s, v1, o_acc[df], 0, 0, 0);
    }
    __builtin_amdgcn_s_setprio(0);

    // publish next buffer (implicit vmcnt(0)+lgkmcnt(0) drain), close this one
    __syncthreads();
  }

  // epilogue: ctx[b][s][h][d] = o_acc / l
  float linv = 1.f / lrow;
  const int b = bh >> 4, h = bh & 15;
#pragma unroll
  for (int r = 0; r < 4; r++) {
    int q = q0 + g * 4 + r;
    float inv = __shfl(linv, g * 4 + r);
#pragma unroll
    for (int df = 0; df < 4; df++) {
      int d = df * 16 + qi;
      size_t off = (((size_t)b * 2048 + q) * 16 + h) * 64 + d;
      ctx[off] = f2bf(o_acc[df][r] * inv);
    }
  }
}

extern "C" void kernel_launch(void* const* d_in, const int* in_sizes, int n_in,
                              void* d_out, int out_size, void* d_ws, size_t ws_size,
                              hipStream_t stream) {
  const float* q  = (const float*)d_in[0];
  const float* k  = (const float*)d_in[1];
  const float* v  = (const float*)d_in[2];
  const float* Wq = (const float*)d_in[3];
  const float* bq = (const float*)d_in[4];
  const float* Wk = (const float*)d_in[5];
  const float* bk = (const float*)d_in[6];
  const float* Wv = (const float*)d_in[7];
  const float* bv = (const float*)d_in[8];
  const float* Wo = (const float*)d_in[9];
  const float* bo = (const float*)d_in[10];

  const size_t MSZ = (size_t)8192 * 1024;
  const size_t WSZ = (size_t)1024 * 1024;
  char* ws = (char*)d_ws;
  ushort* Xbuf = (ushort*)ws;
  ushort* w16[4];
  w16[0] = Xbuf + MSZ;
  w16[1] = w16[0] + WSZ;
  w16[2] = w16[1] + WSZ;
  w16[3] = w16[2] + WSZ;
  ushort* Qhb = w16[3] + WSZ;
  ushort* Khb = Qhb + MSZ;
  ushort* Vtb = Khb + MSZ;
  ushort* ctx = Xbuf;

  const float* Wsrc[4] = {Wq, Wk, Wv, Wo};
  for (int i = 0; i < 4; i++)
    cvt_kernel<<<512, 256, 0, stream>>>(Wsrc[i], w16[i], (int)(WSZ / 4));

  cvt_kernel<<<2048, 256, 0, stream>>>(q, Xbuf, (int)(MSZ / 4));
  gemm_bt<0><<<512, 256, 0, stream>>>(Xbuf, w16[0], bq, Qhb);
  cvt_kernel<<<2048, 256, 0, stream>>>(k, Xbuf, (int)(MSZ / 4));
  gemm_bt<0><<<512, 256, 0, stream>>>(Xbuf, w16[1], bk, Khb);
  cvt_kernel<<<2048, 256, 0, stream>>>(v, Xbuf, (int)(MSZ / 4));
  gemm_bt<1><<<512, 256, 0, stream>>>(Xbuf, w16[2], bv, Vtb);

  attn_kernel<<<dim3(2048), 256, 0, stream>>>(Qhb, Khb, Vtb, ctx);

  gemm_bt<2><<<512, 256, 0, stream>>>(ctx, w16[3], bo, (float*)d_out);
}

// Round 7
// 333.951 us; speedup vs baseline: 1.1352x; 1.0079x over previous
//
#include <hip/hip_runtime.h>
#include <hip/hip_bf16.h>

// MultiSelfAttention: B=4, S=2048, D_MODEL=1024, H=16, Dk=64.
// cvt fp32->bf16 -> QKV proj GEMMs (bf16 MFMA) -> flash attention
// (double-buffered LDS staging, XCD-swizzled grid, 8-wave blocks,
//  swapped QK^T, in-register P, defer-max) -> O proj GEMM -> fp32 out.

typedef __attribute__((ext_vector_type(8))) short short8;
typedef __attribute__((ext_vector_type(4))) float f32x4;

#define DEV __device__ __forceinline__

DEV ushort f2bf(float f) {
  union { float f; unsigned u; } v; v.f = f;
  return (ushort)((v.u + 0x7fffu + ((v.u >> 16) & 1u)) >> 16);
}

DEV void gload_lds16(const void* g, void* lds) {
  __builtin_amdgcn_global_load_lds(
      (const __attribute__((address_space(1))) void*)g,
      (__attribute__((address_space(3))) void*)lds, 16, 0, 0);
}

// ---------------- fp32 -> bf16 convert ----------------
__global__ void cvt_kernel(const float* __restrict__ in, ushort* __restrict__ out, int n4) {
  int stride = gridDim.x * blockDim.x;
  for (int i = blockIdx.x * blockDim.x + threadIdx.x; i < n4; i += stride) {
    float4 v = ((const float4*)in)[i];
    ushort4 o;
    o.x = f2bf(v.x); o.y = f2bf(v.y); o.z = f2bf(v.z); o.w = f2bf(v.w);
    ((ushort4*)out)[i] = o;
  }
}

// ---------------- GEMM: C[m,n] = sum_k X[m,k]*W[n,k] + bias[n] ----------------
// MODE 0: out bf16 [b*16+h][s][d]   (Q,K head layout)
// MODE 1: out bf16 [b*16+h][d][s]   (V transposed layout)
// MODE 2: out fp32 [m][n]           (final output)
template<int MODE>
__global__ __launch_bounds__(256) void gemm_bt(
    const ushort* __restrict__ X, const ushort* __restrict__ W,
    const float* __restrict__ bias, void* __restrict__ out)
{
  constexpr int K = 1024, N = 1024;
  __shared__ __align__(16) ushort As[128 * 32];
  __shared__ __align__(16) ushort Bs[128 * 32];
  const int t = threadIdx.x;
  const int w = t >> 6, l = t & 63;
  const int bid = blockIdx.x;
  const int m0 = (bid >> 3) * 128, n0 = (bid & 7) * 128;
  const int wm = (w >> 1) * 64, wn = (w & 1) * 64;

  const f32x4 zero = {0.f, 0.f, 0.f, 0.f};
  f32x4 acc[4][4];
#pragma unroll
  for (int i = 0; i < 4; i++)
#pragma unroll
    for (int j = 0; j < 4; j++) acc[i][j] = zero;

  const int srow = l >> 2;
  const int scolb = (l & 3) * 16;

  for (int kt = 0; kt < K; kt += 32) {
    __syncthreads();
#pragma unroll
    for (int c = w; c < 8; c += 4) {
      int row = c * 16 + srow;
      gload_lds16((const char*)X + ((size_t)(m0 + row) * K + kt) * 2 + scolb,
                  (char*)As + c * 1024);
      gload_lds16((const char*)W + ((size_t)(n0 + row) * K + kt) * 2 + scolb,
                  (char*)Bs + c * 1024);
    }
    __syncthreads();

    short8 af[4], bf[4];
#pragma unroll
    for (int i = 0; i < 4; i++) {
      af[i] = *(const short8*)((const char*)As + (wm + i * 16 + (l & 15)) * 64 + (l >> 4) * 16);
      bf[i] = *(const short8*)((const char*)Bs + (wn + i * 16 + (l & 15)) * 64 + (l >> 4) * 16);
    }
#pragma unroll
    for (int i = 0; i < 4; i++)
#pragma unroll
      for (int j = 0; j < 4; j++)
        acc[i][j] = __builtin_amdgcn_mfma_f32_16x16x32_bf16(af[i], bf[j], acc[i][j], 0, 0, 0);
  }

#pragma unroll
  for (int i = 0; i < 4; i++) {
    int mbase = m0 + wm + i * 16 + ((l >> 4) << 2);
#pragma unroll
    for (int j = 0; j < 4; j++) {
      int n = n0 + wn + j * 16 + (l & 15);
      float bv = bias[n];
#pragma unroll
      for (int r = 0; r < 4; r++) {
        int m = mbase + r;
        float v = acc[i][j][r] + bv;
        if (MODE == 2) {
          ((float*)out)[(size_t)m * N + n] = v;
        } else {
          int b = m >> 11, s = m & 2047;
          int h = n >> 6, d = n & 63;
          size_t off;
          if (MODE == 0) off = ((size_t)(b * 16 + h) * 2048 + s) * 64 + d;
          else           off = ((size_t)(b * 16 + h) * 64 + d) * 2048 + s;
          ((ushort*)out)[off] = f2bf(v);
        }
      }
    }
  }
}

// ---------------- Flash attention (dbuf staging, XCD swizzle, 8-wave, swapped QK^T) ----------------
// Qh,Kh: [64][2048][64] bf16.  Vt: [64][64][2048] bf16.  ctx: [4][2048][16][64] bf16.
// 8 waves x 16 q-rows = 128 q-rows/block; 1024 blocks = exactly 4 blocks/CU
// (32 waves/CU, single generation). XCD-swizzled so each XCD's L2 serves 8 bh
// (4 MB KV working set). KV tiles of 64, double-buffered in LDS: STAGE(next)
// issued before compute(cur), one barrier per tile. Scores in log2 domain.
__global__ __launch_bounds__(512, 4) void attn_kernel(
    const ushort* __restrict__ Qh, const ushort* __restrict__ Kh,
    const ushort* __restrict__ Vt, ushort* __restrict__ ctx)
{
  __shared__ __align__(16) ushort Ks[2 * 64 * 64];
  __shared__ __align__(16) ushort Vs[2 * 64 * 64];
  const int t = threadIdx.x, w = t >> 6, l = t & 63;
  const int g = l >> 4, g1 = g >> 1, g0 = g & 1, qi = l & 15;
  // XCD-aware bijective swizzle: physical p -> logical (p%8)*128 + p/8.
  // XCD x then owns logical ids [128x, 128x+128) = bh [8x, 8x+8) entirely.
  const int p = blockIdx.x;
  const int logical = (p & 7) * 128 + (p >> 3);
  const int bh = logical >> 4;
  const int q0 = (logical & 15) * 128 + w * 16;
  const ushort* Qb = Qh + (size_t)bh * 2048 * 64;
  const ushort* Kb = Kh + (size_t)bh * 2048 * 64;
  const ushort* Vb = Vt + (size_t)bh * 64 * 2048;

  // Q fragment (B operand: col=q=qi, k=d=g*8+j), pre-scaled by log2(e)/8
  short8 qa[2];
  {
    const ushort* p_ = Qb + (size_t)(q0 + qi) * 64 + g * 8;
    qa[0] = *(const short8*)(p_);
    qa[1] = *(const short8*)(p_ + 32);
    const float SC = 0.18033688f;  // log2(e)/8
#pragma unroll
    for (int h = 0; h < 2; h++)
#pragma unroll
      for (int j = 0; j < 8; j++) {
        union { float f; unsigned u; } v;
        v.u = ((unsigned)(ushort)qa[h][j]) << 16;
        v.f *= SC;
        qa[h][j] = (short)f2bf(v.f);
      }
  }

  const f32x4 zero = {0.f, 0.f, 0.f, 0.f};
  f32x4 o_acc[4];
#pragma unroll
  for (int i = 0; i < 4; i++) o_acc[i] = zero;
  float m = -1e30f, lrow = 0.f;  // per-lane state for q = qi (log2 domain)

  // staging: 8 waves x (1 K-load + 1 V-load)/thread per tile; wave w stages
  // 8-row chunk w of each. LDS linear dest, pre-swizzled global source
  // (swz: byte ^= (row&7)<<4).
  const int srow8 = l >> 3;                       // row within 8-row chunk
  const int scolb = ((l & 7) ^ (l >> 3)) << 4;    // pre-swizzled byte col
  const char* kgp = (const char*)Kb + (size_t)(w * 8 + srow8) * 128 + scolb;
  const char* vgp = (const char*)Vb + (size_t)(w * 8 + srow8) * 4096 + scolb;
  char* ksw = (char*)Ks + w * 1024;
  char* vsw = (char*)Vs + w * 1024;

  // prologue: stage tile 0 into buffer 0
  gload_lds16(kgp, ksw);
  gload_lds16(vgp, vsw);
  __syncthreads();

  for (int it = 0; it < 32; it++) {
    const int cur = it & 1;
    // issue next-tile staging into the other buffer (its readers finished at
    // the previous barrier); lands before anyone reads it (barrier below
    // drains vmcnt).
    if (it < 31) {
      size_t kv = (size_t)(it + 1);
      gload_lds16(kgp + kv * 8192, ksw + (cur ^ 1) * 8192);
      gload_lds16(vgp + kv * 128, vsw + (cur ^ 1) * 8192);
    }
    const char* KsB = (const char*)Ks + cur * 8192;
    const char* VsB = (const char*)Vs + cur * 8192;

    // S^T = K Q^T  (D: row=kv=16*kvf+g*4+r, col=q=qi), log2 domain
    f32x4 sf[4];
    __builtin_amdgcn_s_setprio(1);
#pragma unroll
    for (int kvf = 0; kvf < 4; kvf++) {
      int row = kvf * 16 + qi;
      int sw = (row & 7) << 4;
      int base = row * 128 + g * 16;
      short8 k0 = *(const short8*)(KsB + (base ^ sw));
      short8 k1 = *(const short8*)(KsB + ((base + 64) ^ sw));
      f32x4 s = zero;
      s = __builtin_amdgcn_mfma_f32_16x16x32_bf16(k0, qa[0], s, 0, 0, 0);
      s = __builtin_amdgcn_mfma_f32_16x16x32_bf16(k1, qa[1], s, 0, 0, 0);
      sf[kvf] = s;
    }
    __builtin_amdgcn_s_setprio(0);

    // online softmax, in-lane over 16 kv + 2 shfls across kv-groups
    float pmax = -1e30f;
#pragma unroll
    for (int kvf = 0; kvf < 4; kvf++)
#pragma unroll
      for (int r = 0; r < 4; r++) pmax = fmaxf(pmax, sf[kvf][r]);
    pmax = fmaxf(pmax, __shfl_xor(pmax, 16));
    pmax = fmaxf(pmax, __shfl_xor(pmax, 32));

    if (__any(pmax > m + 8.f)) {  // defer-max: rescale only when needed
      float mnew = fmaxf(m, pmax);
      float facq = exp2f(m - mnew);
      m = mnew;
      lrow *= facq;
#pragma unroll
      for (int r = 0; r < 4; r++) {
        float f = __shfl(facq, g * 4 + r);
#pragma unroll
        for (int df = 0; df < 4; df++) o_acc[df][r] *= f;
      }
    }

    float lsum = 0.f;
#pragma unroll
    for (int kvf = 0; kvf < 4; kvf++)
#pragma unroll
      for (int r = 0; r < 4; r++) {
        float p_ = exp2f(sf[kvf][r] - m);
        sf[kvf][r] = p_;
        lsum += p_;
      }
    lsum += __shfl_xor(lsum, 16);
    lsum += __shfl_xor(lsum, 32);
    lrow += lsum;

    // pack P to bf16 pairs: w8[kvf][p] = kv pair (16*kvf+4*g+2p, +1)
    unsigned w8[4][2];
#pragma unroll
    for (int kvf = 0; kvf < 4; kvf++)
#pragma unroll
      for (int pp = 0; pp < 2; pp++)
        asm("v_cvt_pk_bf16_f32 %0, %1, %2"
            : "=v"(w8[kvf][pp]) : "v"(sf[kvf][2 * pp]), "v"(sf[kvf][2 * pp + 1]));

    // redistribute to PV A-frag layout: lane needs kv = 32h + 8g + {0..7} for its q
    unsigned pw[2][4];
#pragma unroll
    for (int c2 = 0; c2 < 2; c2++)
#pragma unroll
      for (int c1 = 0; c1 < 2; c1++)
#pragma unroll
        for (int c0 = 0; c0 < 2; c0++) {
          unsigned prov = w8[2 * c2 + (c0 ^ g0)][c1];
          int src = (((g0 << 1) | (c0 ^ g1)) << 4) + qi;
          unsigned r = (unsigned)__shfl((int)prov, src);
          if (g1 == 0) pw[c2][(c0 << 1) | c1] = r;
          else         pw[c2][((c0 ^ 1) << 1) | c1] = r;
        }
    union { unsigned u[4]; short8 s; } pa0, pa1;
#pragma unroll
    for (int i = 0; i < 4; i++) { pa0.u[i] = pw[0][i]; pa1.u[i] = pw[1][i]; }

    // O += P V   (A=P: row=q=qi, k=kv; B=Vs[d][kv]: col=d, k=kv)
    __builtin_amdgcn_s_setprio(1);
#pragma unroll
    for (int df = 0; df < 4; df++) {
      int row = df * 16 + qi;
      int sw = (row & 7) << 4;
      int base = row * 128 + g * 16;
      short8 v0 = *(const short8*)(VsB + (base ^ sw));
      short8 v1 = *(const short8*)(VsB + ((base + 64) ^ sw));
      o_acc[df] = __builtin_amdgcn_mfma_f32_16x16x32_bf16(pa0.s, v0, o_acc[df], 0, 0, 0);
      o_acc[df] = __builtin_amdgcn_mfma_f32_16x16x32_bf16(pa1.s, v1, o_acc[df], 0, 0, 0);
    }
    __builtin_amdgcn_s_setprio(0);

    // publish next buffer (implicit vmcnt(0)+lgkmcnt(0) drain), close this one
    __syncthreads();
  }

  // epilogue: ctx[b][s][h][d] = o_acc / l
  float linv = 1.f / lrow;
  const int b = bh >> 4, h = bh & 15;
#pragma unroll
  for (int r = 0; r < 4; r++) {
    int q = q0 + g * 4 + r;
    float inv = __shfl(linv, g * 4 + r);
#pragma unroll
    for (int df = 0; df < 4; df++) {
      int d = df * 16 + qi;
      size_t off = (((size_t)b * 2048 + q) * 16 + h) * 64 + d;
      ctx[off] = f2bf(o_acc[df][r] * inv);
    }
  }
}

extern "C" void kernel_launch(void* const* d_in, const int* in_sizes, int n_in,
                              void* d_out, int out_size, void* d_ws, size_t ws_size,
                              hipStream_t stream) {
  const float* q  = (const float*)d_in[0];
  const float* k  = (const float*)d_in[1];
  const float* v  = (const float*)d_in[2];
  const float* Wq = (const float*)d_in[3];
  const float* bq = (const float*)d_in[4];
  const float* Wk = (const float*)d_in[5];
  const float* bk = (const float*)d_in[6];
  const float* Wv = (const float*)d_in[7];
  const float* bv = (const float*)d_in[8];
  const float* Wo = (const float*)d_in[9];
  const float* bo = (const float*)d_in[10];

  const size_t MSZ = (size_t)8192 * 1024;
  const size_t WSZ = (size_t)1024 * 1024;
  char* ws = (char*)d_ws;
  ushort* Xbuf = (ushort*)ws;
  ushort* w16[4];
  w16[0] = Xbuf + MSZ;
  w16[1] = w16[0] + WSZ;
  w16[2] = w16[1] + WSZ;
  w16[3] = w16[2] + WSZ;
  ushort* Qhb = w16[3] + WSZ;
  ushort* Khb = Qhb + MSZ;
  ushort* Vtb = Khb + MSZ;
  ushort* ctx = Xbuf;

  const float* Wsrc[4] = {Wq, Wk, Wv, Wo};
  for (int i = 0; i < 4; i++)
    cvt_kernel<<<512, 256, 0, stream>>>(Wsrc[i], w16[i], (int)(WSZ / 4));

  cvt_kernel<<<2048, 256, 0, stream>>>(q, Xbuf, (int)(MSZ / 4));
  gemm_bt<0><<<512, 256, 0, stream>>>(Xbuf, w16[0], bq, Qhb);
  cvt_kernel<<<2048, 256, 0, stream>>>(k, Xbuf, (int)(MSZ / 4));
  gemm_bt<0><<<512, 256, 0, stream>>>(Xbuf, w16[1], bk, Khb);
  cvt_kernel<<<2048, 256, 0, stream>>>(v, Xbuf, (int)(MSZ / 4));
  gemm_bt<1><<<512, 256, 0, stream>>>(Xbuf, w16[2], bv, Vtb);

  attn_kernel<<<dim3(1024), 512, 0, stream>>>(Qhb, Khb, Vtb, ctx);

  gemm_bt<2><<<512, 256, 0, stream>>>(ctx, w16[3], bo, (float*)d_out);
}

// Round 8
// 271.150 us; speedup vs baseline: 1.3982x; 1.2316x over previous
//
#include <hip/hip_runtime.h>
#include <hip/hip_bf16.h>

// MultiSelfAttention: B=4, S=2048, D_MODEL=1024, H=16, Dk=64.
// cvt fp32->bf16 -> QKV proj GEMMs (bf16 MFMA) -> flash attention
// (32x32 MFMA, dbuf LDS staging, XCD swizzle, swapped QK^T, in-register P
//  via cvt_pk+permlane32_swap, defer-max) -> O proj GEMM -> fp32 out.

typedef __attribute__((ext_vector_type(8))) short short8;
typedef __attribute__((ext_vector_type(4))) float f32x4;
typedef __attribute__((ext_vector_type(16))) float f32x16;

#define DEV __device__ __forceinline__

DEV ushort f2bf(float f) {
  union { float f; unsigned u; } v; v.f = f;
  return (ushort)((v.u + 0x7fffu + ((v.u >> 16) & 1u)) >> 16);
}

DEV void gload_lds16(const void* g, void* lds) {
  __builtin_amdgcn_global_load_lds(
      (const __attribute__((address_space(1))) void*)g,
      (__attribute__((address_space(3))) void*)lds, 16, 0, 0);
}

// ---------------- fp32 -> bf16 convert ----------------
__global__ void cvt_kernel(const float* __restrict__ in, ushort* __restrict__ out, int n4) {
  int stride = gridDim.x * blockDim.x;
  for (int i = blockIdx.x * blockDim.x + threadIdx.x; i < n4; i += stride) {
    float4 v = ((const float4*)in)[i];
    ushort4 o;
    o.x = f2bf(v.x); o.y = f2bf(v.y); o.z = f2bf(v.z); o.w = f2bf(v.w);
    ((ushort4*)out)[i] = o;
  }
}

// ---------------- GEMM: C[m,n] = sum_k X[m,k]*W[n,k] + bias[n] ----------------
// MODE 0: out bf16 [b*16+h][s][d]   (Q,K head layout)
// MODE 1: out bf16 [b*16+h][d][s]   (V transposed layout)
// MODE 2: out fp32 [m][n]           (final output)
template<int MODE>
__global__ __launch_bounds__(256) void gemm_bt(
    const ushort* __restrict__ X, const ushort* __restrict__ W,
    const float* __restrict__ bias, void* __restrict__ out)
{
  constexpr int K = 1024, N = 1024;
  __shared__ __align__(16) ushort As[128 * 32];
  __shared__ __align__(16) ushort Bs[128 * 32];
  const int t = threadIdx.x;
  const int w = t >> 6, l = t & 63;
  const int bid = blockIdx.x;
  const int m0 = (bid >> 3) * 128, n0 = (bid & 7) * 128;
  const int wm = (w >> 1) * 64, wn = (w & 1) * 64;

  const f32x4 zero = {0.f, 0.f, 0.f, 0.f};
  f32x4 acc[4][4];
#pragma unroll
  for (int i = 0; i < 4; i++)
#pragma unroll
    for (int j = 0; j < 4; j++) acc[i][j] = zero;

  const int srow = l >> 2;
  const int scolb = (l & 3) * 16;

  for (int kt = 0; kt < K; kt += 32) {
    __syncthreads();
#pragma unroll
    for (int c = w; c < 8; c += 4) {
      int row = c * 16 + srow;
      gload_lds16((const char*)X + ((size_t)(m0 + row) * K + kt) * 2 + scolb,
                  (char*)As + c * 1024);
      gload_lds16((const char*)W + ((size_t)(n0 + row) * K + kt) * 2 + scolb,
                  (char*)Bs + c * 1024);
    }
    __syncthreads();

    short8 af[4], bf[4];
#pragma unroll
    for (int i = 0; i < 4; i++) {
      af[i] = *(const short8*)((const char*)As + (wm + i * 16 + (l & 15)) * 64 + (l >> 4) * 16);
      bf[i] = *(const short8*)((const char*)Bs + (wn + i * 16 + (l & 15)) * 64 + (l >> 4) * 16);
    }
#pragma unroll
    for (int i = 0; i < 4; i++)
#pragma unroll
      for (int j = 0; j < 4; j++)
        acc[i][j] = __builtin_amdgcn_mfma_f32_16x16x32_bf16(af[i], bf[j], acc[i][j], 0, 0, 0);
  }

#pragma unroll
  for (int i = 0; i < 4; i++) {
    int mbase = m0 + wm + i * 16 + ((l >> 4) << 2);
#pragma unroll
    for (int j = 0; j < 4; j++) {
      int n = n0 + wn + j * 16 + (l & 15);
      float bv = bias[n];
#pragma unroll
      for (int r = 0; r < 4; r++) {
        int m = mbase + r;
        float v = acc[i][j][r] + bv;
        if (MODE == 2) {
          ((float*)out)[(size_t)m * N + n] = v;
        } else {
          int b = m >> 11, s = m & 2047;
          int h = n >> 6, d = n & 63;
          size_t off;
          if (MODE == 0) off = ((size_t)(b * 16 + h) * 2048 + s) * 64 + d;
          else           off = ((size_t)(b * 16 + h) * 64 + d) * 2048 + s;
          ((ushort*)out)[off] = f2bf(v);
        }
      }
    }
  }
}

// ---------------- Flash attention (32x32 MFMA, dbuf, XCD swizzle) ----------------
// Qh,Kh: [64][2048][64] bf16.  Vt: [64][64][2048] bf16.  ctx: [4][2048][16][64] bf16.
// 4 waves x 32 q-rows = 128 q-rows/block; 1024 blocks (4/CU). KV tiles of 64,
// K and V (V in [d][kv] layout) double-buffered in LDS with XOR swizzle
// (byte ^= (row&7)<<4, pre-swizzled global source). Swapped QK^T in 32x32x16
// fragments: S^T D-layout => lane holds q=l&31, 32 kv values in-register ->
// softmax is in-lane + one shfl_xor(32). P->PV-A-frag via 16 cvt_pk +
// 8 permlane32_swap (VALU only). Scores in log2 domain (Q pre-scaled).
__global__ __launch_bounds__(256, 4) void attn_kernel(
    const ushort* __restrict__ Qh, const ushort* __restrict__ Kh,
    const ushort* __restrict__ Vt, ushort* __restrict__ ctx)
{
  __shared__ __align__(16) ushort Ks[2 * 64 * 64];   // [buf][kv][d] swizzled
  __shared__ __align__(16) ushort Vs[2 * 64 * 64];   // [buf][d][kv] swizzled
  const int t = threadIdx.x, w = t >> 6, l = t & 63;
  const int hf = l >> 5, ln = l & 31;
  // XCD-aware bijective swizzle: physical p -> logical (p%8)*128 + p/8.
  const int p = blockIdx.x;
  const int logical = (p & 7) * 128 + (p >> 3);
  const int bh = logical >> 4;
  const int q0 = (logical & 15) * 128 + w * 32;
  const ushort* Qb = Qh + (size_t)bh * 2048 * 64;
  const ushort* Kb = Kh + (size_t)bh * 2048 * 64;
  const ushort* Vb = Vt + (size_t)bh * 64 * 2048;

  // Q B-frag: lane provides B[k = 16s+8hf+j][col = q = ln]; prescale log2(e)/8
  short8 qb[4];
  {
    const ushort* qp = Qb + (size_t)(q0 + ln) * 64 + hf * 8;
    const float SC = 0.18033688f;  // log2(e)/8
#pragma unroll
    for (int s = 0; s < 4; s++) {
      short8 v = *(const short8*)(qp + s * 16);
#pragma unroll
      for (int j = 0; j < 8; j++) {
        union { float f; unsigned u; } x;
        x.u = ((unsigned)(ushort)v[j]) << 16;
        x.f *= SC;
        v[j] = (short)f2bf(x.f);
      }
      qb[s] = v;
    }
  }

  f32x16 o_acc[2];
#pragma unroll
  for (int dn = 0; dn < 2; dn++)
#pragma unroll
    for (int r = 0; r < 16; r++) o_acc[dn][r] = 0.f;
  f32x16 z16;
#pragma unroll
  for (int r = 0; r < 16; r++) z16[r] = 0.f;
  float m = -1e30f, lrow = 0.f;  // per-lane state for q = ln (log2 domain)

  // staging: 256 threads stage K tile (64 kv x 64 d) + V tile (64 d x 64 kv),
  // 4 x 16B loads/thread. LDS dest linear (== base + lane*16 per wave);
  // global source pre-swizzled: byte col = (j*16) ^ ((row&7)<<4).
  const int srow = t >> 3;                         // 0..31 (rows srow, srow+32)
  const int ssw = (((t & 7) ^ (srow & 7)) << 4);   // pre-swizzled byte col
  const char* kg = (const char*)Kb + (size_t)srow * 128 + ssw;
  const char* vg = (const char*)Vb + (size_t)srow * 4096 + ssw;
  char* kld = (char*)Ks + (size_t)t * 16;
  char* vld = (char*)Vs + (size_t)t * 16;

#define STAGE(buf_, kv0_) do {                                                  \
    gload_lds16(kg + (size_t)(kv0_) * 128, kld + (buf_) * 8192);                \
    gload_lds16(kg + (size_t)(kv0_) * 128 + 32 * 128, kld + (buf_) * 8192 + 4096); \
    gload_lds16(vg + (size_t)(kv0_) * 2, vld + (buf_) * 8192);                  \
    gload_lds16(vg + (size_t)(kv0_) * 2 + (size_t)32 * 4096, vld + (buf_) * 8192 + 4096); \
  } while (0)

  // prologue: stage tile 0 into buffer 0
  STAGE(0, 0);
  __syncthreads();

  const int rsw = (ln & 7) << 4;  // read-side row-XOR (K row=32f+ln, V row=32dn+ln)

  for (int it = 0; it < 32; it++) {
    const int cur = it & 1;
    if (it < 31) STAGE(cur ^ 1, (it + 1) * 64);
    const char* KsB = (const char*)Ks + cur * 8192;
    const char* VsB = (const char*)Vs + cur * 8192;

    // S^T = K Q^T: D[row=kv][col=q=ln]; lane kv rows = (r&3)+8*(r>>2)+4hf+32f
    f32x16 sf[2];
    __builtin_amdgcn_s_setprio(1);
#pragma unroll
    for (int f = 0; f < 2; f++) {
      f32x16 s_ = z16;
#pragma unroll
      for (int s = 0; s < 4; s++) {
        short8 kf = *(const short8*)(KsB + (32 * f + ln) * 128 + ((16 * hf + 32 * s) ^ rsw));
        s_ = __builtin_amdgcn_mfma_f32_32x32x16_bf16(kf, qb[s], s_, 0, 0, 0);
      }
      sf[f] = s_;
    }
    __builtin_amdgcn_s_setprio(0);

    // online softmax: 32 in-lane values + one xor-32 exchange
    float pmax = -1e30f;
#pragma unroll
    for (int f = 0; f < 2; f++)
#pragma unroll
      for (int r = 0; r < 16; r++) pmax = fmaxf(pmax, sf[f][r]);
    pmax = fmaxf(pmax, __shfl_xor(pmax, 32));

    if (__any(pmax > m + 8.f)) {  // defer-max: rescale only when needed
      float mnew = fmaxf(m, pmax);
      float facq = exp2f(m - mnew);
      m = mnew;
      lrow *= facq;
#pragma unroll
      for (int r = 0; r < 16; r++) {
        float fr = __shfl(facq, (r & 3) + 8 * (r >> 2) + 4 * hf);
        o_acc[0][r] *= fr;
        o_acc[1][r] *= fr;
      }
    }

    float lsum = 0.f;
#pragma unroll
    for (int f = 0; f < 2; f++)
#pragma unroll
      for (int r = 0; r < 16; r++) {
        float p_ = exp2f(sf[f][r] - m);
        sf[f][r] = p_;
        lsum += p_;
      }
    lsum += __shfl_xor(lsum, 32);
    lrow += lsum;

    // P -> PV A-frags: per f, pack 16 f32 -> 8 words, then 4 permlane32_swap.
    // quad a = 2*rq + half + 8*f holds kv 4a..4a+3; swap(w[rq],w[rq+1]) gives
    // both halves their {own, partner} quads for step s = 2f + s2.
    __builtin_amdgcn_s_setprio(1);
#pragma unroll
    for (int f = 0; f < 2; f++) {
      unsigned wd0, wd1, wd2, wd3, wd4, wd5, wd6, wd7;
      asm("v_cvt_pk_bf16_f32 %0, %1, %2" : "=v"(wd0) : "v"(sf[f][0]),  "v"(sf[f][1]));
      asm("v_cvt_pk_bf16_f32 %0, %1, %2" : "=v"(wd1) : "v"(sf[f][2]),  "v"(sf[f][3]));
      asm("v_cvt_pk_bf16_f32 %0, %1, %2" : "=v"(wd2) : "v"(sf[f][4]),  "v"(sf[f][5]));
      asm("v_cvt_pk_bf16_f32 %0, %1, %2" : "=v"(wd3) : "v"(sf[f][6]),  "v"(sf[f][7]));
      asm("v_cvt_pk_bf16_f32 %0, %1, %2" : "=v"(wd4) : "v"(sf[f][8]),  "v"(sf[f][9]));
      asm("v_cvt_pk_bf16_f32 %0, %1, %2" : "=v"(wd5) : "v"(sf[f][10]), "v"(sf[f][11]));
      asm("v_cvt_pk_bf16_f32 %0, %1, %2" : "=v"(wd6) : "v"(sf[f][12]), "v"(sf[f][13]));
      asm("v_cvt_pk_bf16_f32 %0, %1, %2" : "=v"(wd7) : "v"(sf[f][14]), "v"(sf[f][15]));
      // swap quad rq<->rq+1 word-pairs: after swap, x' = {x_lo, y_lo}, y' = {x_hi, y_hi}
      asm("v_permlane32_swap_b32 %0, %1" : "+v"(wd0), "+v"(wd2));
      asm("v_permlane32_swap_b32 %0, %1" : "+v"(wd1), "+v"(wd3));
      asm("v_permlane32_swap_b32 %0, %1" : "+v"(wd4), "+v"(wd6));
      asm("v_permlane32_swap_b32 %0, %1" : "+v"(wd5), "+v"(wd7));
#pragma unroll
      for (int s2 = 0; s2 < 2; s2++) {
        union { unsigned u[4]; short8 s8; } pa;
        if (s2 == 0) { pa.u[0] = wd0; pa.u[1] = wd1; pa.u[2] = wd2; pa.u[3] = wd3; }
        else         { pa.u[0] = wd4; pa.u[1] = wd5; pa.u[2] = wd6; pa.u[3] = wd7; }
        const int s = 2 * f + s2;
#pragma unroll
        for (int dn = 0; dn < 2; dn++) {
          short8 vf = *(const short8*)(VsB + (32 * dn + ln) * 128 + ((16 * hf + 32 * s) ^ rsw));
          o_acc[dn] = __builtin_amdgcn_mfma_f32_32x32x16_bf16(pa.s8, vf, o_acc[dn], 0, 0, 0);
        }
      }
    }
    __builtin_amdgcn_s_setprio(0);

    // publish next buffer (implicit vmcnt(0)+lgkmcnt(0) drain), close this one
    __syncthreads();
  }
#undef STAGE

  // epilogue: ctx[b][s][h][d] = o_acc / l;  O D-layout: col=d(=dn*32+ln),
  // row=q=(r&3)+8*(r>>2)+4hf
  float linv = 1.f / lrow;
  const int b = bh >> 4, hd = bh & 15;
#pragma unroll
  for (int r = 0; r < 16; r++) {
    int qrow = (r & 3) + 8 * (r >> 2) + 4 * hf;
    float inv = __shfl(linv, qrow);
#pragma unroll
    for (int dn = 0; dn < 2; dn++) {
      int d = dn * 32 + ln;
      size_t off = (((size_t)b * 2048 + (q0 + qrow)) * 16 + hd) * 64 + d;
      ctx[off] = f2bf(o_acc[dn][r] * inv);
    }
  }
}

extern "C" void kernel_launch(void* const* d_in, const int* in_sizes, int n_in,
                              void* d_out, int out_size, void* d_ws, size_t ws_size,
                              hipStream_t stream) {
  const float* q  = (const float*)d_in[0];
  const float* k  = (const float*)d_in[1];
  const float* v  = (const float*)d_in[2];
  const float* Wq = (const float*)d_in[3];
  const float* bq = (const float*)d_in[4];
  const float* Wk = (const float*)d_in[5];
  const float* bk = (const float*)d_in[6];
  const float* Wv = (const float*)d_in[7];
  const float* bv = (const float*)d_in[8];
  const float* Wo = (const float*)d_in[9];
  const float* bo = (const float*)d_in[10];

  const size_t MSZ = (size_t)8192 * 1024;
  const size_t WSZ = (size_t)1024 * 1024;
  char* ws = (char*)d_ws;
  ushort* Xbuf = (ushort*)ws;
  ushort* w16[4];
  w16[0] = Xbuf + MSZ;
  w16[1] = w16[0] + WSZ;
  w16[2] = w16[1] + WSZ;
  w16[3] = w16[2] + WSZ;
  ushort* Qhb = w16[3] + WSZ;
  ushort* Khb = Qhb + MSZ;
  ushort* Vtb = Khb + MSZ;
  ushort* ctx = Xbuf;

  const float* Wsrc[4] = {Wq, Wk, Wv, Wo};
  for (int i = 0; i < 4; i++)
    cvt_kernel<<<512, 256, 0, stream>>>(Wsrc[i], w16[i], (int)(WSZ / 4));

  cvt_kernel<<<2048, 256, 0, stream>>>(q, Xbuf, (int)(MSZ / 4));
  gemm_bt<0><<<512, 256, 0, stream>>>(Xbuf, w16[0], bq, Qhb);
  cvt_kernel<<<2048, 256, 0, stream>>>(k, Xbuf, (int)(MSZ / 4));
  gemm_bt<0><<<512, 256, 0, stream>>>(Xbuf, w16[1], bk, Khb);
  cvt_kernel<<<2048, 256, 0, stream>>>(v, Xbuf, (int)(MSZ / 4));
  gemm_bt<1><<<512, 256, 0, stream>>>(Xbuf, w16[2], bv, Vtb);

  attn_kernel<<<dim3(1024), 256, 0, stream>>>(Qhb, Khb, Vtb, ctx);

  gemm_bt<2><<<512, 256, 0, stream>>>(ctx, w16[3], bo, (float*)d_out);
}